// Round 3
// baseline (1957.548 us; speedup 1.0000x reference)
//
#include <hip/hip_runtime.h>
#include <math.h>

// Problem constants (reference: H, W, D = 96, 80, 128; KS=1 -> 27 offsets)
#define HH 96
#define WW 80
#define DD 128
#define NVOX (HH * WW * DD)   // 983040

struct W27 { float w[27]; };

// cv[o][v] = -|src(z+dz, y+dy, x+dx) or 0  -  tgt(v)|, o = (dz+1)*9+(dy+1)*3+(dx+1)
__global__ void cv_kernel(const float* __restrict__ src, const float* __restrict__ tgt,
                          float* __restrict__ cv) {
  int v = blockIdx.x * blockDim.x + threadIdx.x;
  if (v >= NVOX) return;
  int x = v % DD;
  int y = (v / DD) % WW;
  int z = v / (DD * WW);
  float t = tgt[v];
  int o = 0;
  #pragma unroll
  for (int dz = -1; dz <= 1; ++dz) {
    int zz = z + dz;
    #pragma unroll
    for (int dy = -1; dy <= 1; ++dy) {
      int yy = y + dy;
      #pragma unroll
      for (int dx = -1; dx <= 1; ++dx) {
        int xx = x + dx;
        float s = 0.f;
        if ((unsigned)zz < (unsigned)HH && (unsigned)yy < (unsigned)WW &&
            (unsigned)xx < (unsigned)DD)
          s = src[(zz * WW + yy) * DD + xx];
        cv[(size_t)o * NVOX + v] = -fabsf(__fsub_rn(s, t));
        ++o;
      }
    }
  }
}

// Depthwise 3x3x3 blur, zero padding, f64 accumulation (correctly-rounded f32
// result — matches an ndimage-style double-accumulating reference conv).
__global__ void blur_kernel(const float* __restrict__ in, float* __restrict__ out,
                            W27 wt) {
  int v = blockIdx.x * blockDim.x + threadIdx.x;
  if (v >= NVOX) return;
  size_t coff = (size_t)blockIdx.y * NVOX;
  int x = v % DD;
  int y = (v / DD) % WW;
  int z = v / (DD * WW);
  const float* __restrict__ p = in + coff;
  double acc = 0.0;
  int o = 0;
  #pragma unroll
  for (int dz = -1; dz <= 1; ++dz) {
    int zz = z + dz;
    #pragma unroll
    for (int dy = -1; dy <= 1; ++dy) {
      int yy = y + dy;
      #pragma unroll
      for (int dx = -1; dx <= 1; ++dx) {
        int xx = x + dx;
        float s = 0.f;
        if ((unsigned)zz < (unsigned)HH && (unsigned)yy < (unsigned)WW &&
            (unsigned)xx < (unsigned)DD)
          s = p[(zz * WW + yy) * DD + xx];
        acc += (double)wt.w[o] * (double)s;
        ++o;
      }
    }
  }
  out[coff + v] = (float)acc;
}

// coupled[o] = cv[o] - coeff * ||flow - offset_o||^2   (all rounds un-fused,
// matching numpy elementwise rounding). The reference's argmax is
//   p = softmax(coupled/temp) in f32;  oh = (p == p.max)
// which is equivalent to exact-equality ties on y_o = f32(coupled_o / temp):
// the division's coarse f32 grid at |y|~1e4 merges 1-ulp near-ties into
// exact ties (which then SUM their offsets).
__global__ void flow_kernel(const float* __restrict__ cv, const float* __restrict__ fin,
                            float coeff, int couple, float* __restrict__ fout) {
  int v = blockIdx.x * blockDim.x + threadIdx.x;
  if (v >= NVOX) return;
  float f0 = 0.f, f1 = 0.f, f2 = 0.f;
  if (couple) {
    f0 = fin[v];
    f1 = fin[NVOX + v];
    f2 = fin[2 * NVOX + v];
  }
  float y27[27];
  float best = -INFINITY;
  #pragma unroll
  for (int o = 0; o < 27; ++o) {
    float cvv = cv[(size_t)o * NVOX + v];
    if (couple) {
      float oz = (float)(o / 9 - 1);
      float oy = (float)((o / 3) % 3 - 1);
      float ox = (float)(o % 3 - 1);
      float dz = __fsub_rn(f0, oz);
      float dy = __fsub_rn(f1, oy);
      float dx = __fsub_rn(f2, ox);
      float sz = __fmul_rn(dz, dz);
      float sy = __fmul_rn(dy, dy);
      float sx = __fmul_rn(dx, dx);
      float d2 = __fadd_rn(__fadd_rn(sz, sy), sx);
      float prod = __fmul_rn(coeff, d2);
      cvv = __fsub_rn(cvv, prod);
    }
    float yv = __fdiv_rn(cvv, 5e-5f);   // the tie-merging quantization step
    y27[o] = yv;
    best = fmaxf(best, yv);
  }
  float s0 = 0.f, s1 = 0.f, s2 = 0.f;
  #pragma unroll
  for (int o = 0; o < 27; ++o) {
    if (y27[o] == best) {
      s0 += (float)(o / 9 - 1);
      s1 += (float)((o / 3) % 3 - 1);
      s2 += (float)(o % 3 - 1);
    }
  }
  fout[v] = s0;
  fout[NVOX + v] = s1;
  fout[2 * NVOX + v] = s2;
}

extern "C" void kernel_launch(void* const* d_in, const int* in_sizes, int n_in,
                              void* d_out, int out_size, void* d_ws, size_t ws_size,
                              hipStream_t stream) {
  const float* src = (const float*)d_in[0];
  const float* tgt = (const float*)d_in[1];
  float* out = (float*)d_out;

  // Workspace layout (needs 54*NVOX floats = ~212.3 MB):
  //   cva: 27N   (cost volume ping; dead after 3rd cv blur -> reused for flow)
  //   cvb: 27N   (blurred cv, read-only for all 7 argmax stages)
  float* cva = (float*)d_ws;
  float* cvb = cva + (size_t)27 * NVOX;
  float* fa = cva;                       // aliased into dead cva region
  float* fb = cva + (size_t)3 * NVOX;

  // 3^3 Gaussian (sigma=0.5) weights, replicating the reference's f32 path:
  //   g = f32(factor) * f32(exp(-2*d2))            (f32 multiply)
  //   s = numpy PAIRWISE sum of the 27 g's in f32  (8 accs, tree, tail)
  //   w = g / s                                    (f32 divide)
  W27 wt;
  {
    volatile float factor = (float)(1.0 / pow(2.0 * M_PI * 0.25, 1.5));
    float g[27];
    int o = 0;
    for (int i = 0; i < 3; ++i)
      for (int j = 0; j < 3; ++j)
        for (int k = 0; k < 3; ++k) {
          int d2 = (i - 1) * (i - 1) + (j - 1) * (j - 1) + (k - 1) * (k - 1);
          volatile float e = (float)exp(-2.0 * (double)d2);
          volatile float gg = factor * e;   // f32 multiply, rounded
          g[o++] = gg;
        }
    // numpy pairwise_sum for n=27: r[j]=a[j]; r[j]+=a[8+j]; r[j]+=a[16+j];
    // res=((r0+r1)+(r2+r3))+((r4+r5)+(r6+r7)); res+=a[24];+=a[25];+=a[26]
    volatile float r[8];
    for (int j = 0; j < 8; ++j) r[j] = g[j];
    for (int j = 0; j < 8; ++j) r[j] = r[j] + g[8 + j];
    for (int j = 0; j < 8; ++j) r[j] = r[j] + g[16 + j];
    volatile float t01 = r[0] + r[1];
    volatile float t23 = r[2] + r[3];
    volatile float t45 = r[4] + r[5];
    volatile float t67 = r[6] + r[7];
    volatile float h0 = t01 + t23;
    volatile float h1 = t45 + t67;
    volatile float s = h0 + h1;
    s = s + g[24];
    s = s + g[25];
    s = s + g[26];
    for (int t = 0; t < 27; ++t) {
      volatile float w = g[t] / s;          // f32 division
      wt.w[t] = w;
    }
  }

  dim3 blk(256);
  int vb = (NVOX + 255) / 256;  // 3840 blocks per voxel pass

  // 1. cost volume
  cv_kernel<<<vb, blk, 0, stream>>>(src, tgt, cva);
  // 2. blur cv 3x (ping-pong; ends in cvb)
  blur_kernel<<<dim3(vb, 27), blk, 0, stream>>>(cva, cvb, wt);
  blur_kernel<<<dim3(vb, 27), blk, 0, stream>>>(cvb, cva, wt);
  blur_kernel<<<dim3(vb, 27), blk, 0, stream>>>(cva, cvb, wt);
  // 3. initial argmax flow (cva region now dead -> fa/fb live there)
  flow_kernel<<<vb, blk, 0, stream>>>(cvb, nullptr, 0.f, 0, fa);
  blur_kernel<<<dim3(vb, 3), blk, 0, stream>>>(fa, fb, wt);
  blur_kernel<<<dim3(vb, 3), blk, 0, stream>>>(fb, fa, wt);
  blur_kernel<<<dim3(vb, 3), blk, 0, stream>>>(fa, fb, wt);
  // 4. six coupling iterations
  const float coefs[6] = {0.003f, 0.01f, 0.03f, 0.1f, 0.3f, 1.0f};
  for (int it = 0; it < 6; ++it) {
    flow_kernel<<<vb, blk, 0, stream>>>(cvb, fb, coefs[it], 1, fa);
    blur_kernel<<<dim3(vb, 3), blk, 0, stream>>>(fa, fb, wt);
    blur_kernel<<<dim3(vb, 3), blk, 0, stream>>>(fb, fa, wt);
    float* dst = (it == 5) ? out : fb;
    blur_kernel<<<dim3(vb, 3), blk, 0, stream>>>(fa, dst, wt);
  }
}

// Round 4
// 1288.872 us; speedup vs baseline: 1.5188x; 1.5188x over previous
//
#include <hip/hip_runtime.h>
#include <math.h>

// Problem constants (reference: H, W, D = 96, 80, 128; KS=1 -> 27 offsets)
#define HH 96
#define WW 80
#define DD 128
#define SLICE (WW * DD)       // 10240
#define NVOX (HH * WW * DD)   // 983040

struct W27 { float w[27]; };
struct W4d { double w0, w1, w2, w3; };

// Depthwise 3x3x3 Gaussian blur, zero padding, f64 accumulation (result is the
// correctly-rounded f32 conv, order-independent). Each thread owns one (y,x)
// column and marches a z-slab, reusing per-slice 2D partials (center/face/
// corner sums) across the 3 z-taps. The 27 f32 weights collapse to 4 distinct
// values by d^2 symmetry.
// FUSED: input is the cost volume computed on the fly from src/tgt for channel
// offset o=blockIdx.z (saves materializing+re-reading the unblurred cv).
template <bool FUSED>
__global__ void blur_march_kernel(const float* __restrict__ in,
                                  const float* __restrict__ src,
                                  const float* __restrict__ tgt,
                                  float* __restrict__ out,
                                  int zslab, W4d w) {
  const int tid = threadIdx.x;
  const int x = tid & (DD - 1);
  const int y = blockIdx.x * 2 + (tid >> 7);
  const int c = blockIdx.z;
  const int z0 = blockIdx.y * zslab;
  const int z1 = min(z0 + zslab, HH);

  // thread-invariant tap masks / relative offsets for the 3x3 (dy,dx) stencil
  bool m[9];
  int o9[9];
  {
    int jj = 0;
    for (int dy = -1; dy <= 1; ++dy)
      for (int dx = -1; dx <= 1; ++dx) {
        m[jj] = ((unsigned)(y + dy) < WW) && ((unsigned)(x + dx) < DD);
        o9[jj] = dy * DD + dx;
        ++jj;
      }
  }
  int oz = 0, soff = 0;
  bool ms[9];
  if (FUSED) {
    oz = c / 9 - 1;
    int oy = (c / 3) % 3 - 1;
    int ox = c % 3 - 1;
    soff = oz * SLICE + oy * DD + ox;
    int jj = 0;
    for (int dy = -1; dy <= 1; ++dy)
      for (int dx = -1; dx <= 1; ++dx) {
        ms[jj] = ((unsigned)(y + dy + oy) < WW) && ((unsigned)(x + dx + ox) < DD);
        ++jj;
      }
  }

  const int pbase = y * DD + x;
  const float* inc = FUSED ? (const float*)nullptr : (in + (size_t)c * NVOX);

  // 2D partials of one z-slice: c2 = center, f2 = 4 face taps, e2 = 4 corners
  auto load_slice = [&](int zz, double& c2, double& f2, double& e2) {
    c2 = 0.0; f2 = 0.0; e2 = 0.0;
    if ((unsigned)zz >= (unsigned)HH) return;
    float s[9];
    if (!FUSED) {
      const float* b = inc + (size_t)zz * SLICE + pbase;
      #pragma unroll
      for (int j = 0; j < 9; ++j) s[j] = m[j] ? b[o9[j]] : 0.f;
    } else {
      const float* tb = tgt + (size_t)zz * SLICE + pbase;
      const float* sb = src + (size_t)zz * SLICE + pbase + soff;
      const bool zok = ((unsigned)(zz + oz) < (unsigned)HH);
      #pragma unroll
      for (int j = 0; j < 9; ++j) {
        if (m[j]) {
          float tv = tb[o9[j]];
          float sv = (zok && ms[j]) ? sb[o9[j]] : 0.f;
          s[j] = -fabsf(sv - tv);  // cv value (src zero-padded, tgt in-bounds)
        } else {
          s[j] = 0.f;              // blur zero-padding
        }
      }
    }
    double d0 = (double)s[0], d1 = (double)s[1], d2 = (double)s[2],
           d3 = (double)s[3], d4 = (double)s[4], d5 = (double)s[5],
           d6 = (double)s[6], d7 = (double)s[7], d8 = (double)s[8];
    c2 = d4;
    f2 = (d1 + d3) + (d5 + d7);
    e2 = (d0 + d2) + (d6 + d8);
  };

  double cA, fA, eA, cB, fB, eB;
  load_slice(z0 - 1, cA, fA, eA);
  load_slice(z0, cB, fB, eB);
  float* ob = out + (size_t)c * NVOX + pbase;
  for (int z = z0; z < z1; ++z) {
    double cC, fC, eC;
    load_slice(z + 1, cC, fC, eC);
    double faces = fB + (cA + cC);
    double edges = eB + (fA + fC);
    double corners = eA + eC;
    double r = (w.w0 * cB + w.w1 * faces) + (w.w2 * edges + w.w3 * corners);
    ob[(size_t)z * SLICE] = (float)r;
    cA = cB; fA = fB; eA = eB;
    cB = cC; fB = fC; eB = eC;
  }
}

// coupled[o] = cv[o] - coeff * ||flow - offset_o||^2   (all rounds un-fused,
// matching numpy elementwise rounding). Reference argmax = exact-equality ties
// on y_o = f32(coupled_o / temp); the division's coarse f32 grid merges 1-ulp
// near-ties into exact ties (which then SUM their offsets).
__global__ void flow_kernel(const float* __restrict__ cv, const float* __restrict__ fin,
                            float coeff, int couple, float* __restrict__ fout) {
  int v = blockIdx.x * blockDim.x + threadIdx.x;
  if (v >= NVOX) return;
  float f0 = 0.f, f1 = 0.f, f2 = 0.f;
  if (couple) {
    f0 = fin[v];
    f1 = fin[NVOX + v];
    f2 = fin[2 * NVOX + v];
  }
  float y27[27];
  float best = -INFINITY;
  #pragma unroll
  for (int o = 0; o < 27; ++o) {
    float cvv = cv[(size_t)o * NVOX + v];
    if (couple) {
      float oz = (float)(o / 9 - 1);
      float oy = (float)((o / 3) % 3 - 1);
      float ox = (float)(o % 3 - 1);
      float dz = __fsub_rn(f0, oz);
      float dy = __fsub_rn(f1, oy);
      float dx = __fsub_rn(f2, ox);
      float sz = __fmul_rn(dz, dz);
      float sy = __fmul_rn(dy, dy);
      float sx = __fmul_rn(dx, dx);
      float d2 = __fadd_rn(__fadd_rn(sz, sy), sx);
      float prod = __fmul_rn(coeff, d2);
      cvv = __fsub_rn(cvv, prod);
    }
    float yv = __fdiv_rn(cvv, 5e-5f);   // the tie-merging quantization step
    y27[o] = yv;
    best = fmaxf(best, yv);
  }
  float s0 = 0.f, s1 = 0.f, s2 = 0.f;
  #pragma unroll
  for (int o = 0; o < 27; ++o) {
    if (y27[o] == best) {
      s0 += (float)(o / 9 - 1);
      s1 += (float)((o / 3) % 3 - 1);
      s2 += (float)(o % 3 - 1);
    }
  }
  fout[v] = s0;
  fout[NVOX + v] = s1;
  fout[2 * NVOX + v] = s2;
}

extern "C" void kernel_launch(void* const* d_in, const int* in_sizes, int n_in,
                              void* d_out, int out_size, void* d_ws, size_t ws_size,
                              hipStream_t stream) {
  const float* src = (const float*)d_in[0];
  const float* tgt = (const float*)d_in[1];
  float* out = (float*)d_out;

  // Workspace layout (54*NVOX floats = ~212.3 MB):
  //   cv1: 27N  (final blurred cv after pass 3, read-only for all argmax stages)
  //   cv2: 27N  (ping buffer; dead after pass 3 -> flow buffers alias here)
  float* cv1 = (float*)d_ws;
  float* cv2 = cv1 + (size_t)27 * NVOX;
  float* fa = cv2;                       // aliased into dead cv2 region
  float* fb = cv2 + (size_t)3 * NVOX;

  // 3^3 Gaussian (sigma=0.5) weights, replicating the reference's f32 path
  // (factor*exp in f32, numpy pairwise f32 sum, f32 divide).
  W27 wt;
  {
    volatile float factor = (float)(1.0 / pow(2.0 * M_PI * 0.25, 1.5));
    float g[27];
    int o = 0;
    for (int i = 0; i < 3; ++i)
      for (int j = 0; j < 3; ++j)
        for (int k = 0; k < 3; ++k) {
          int d2 = (i - 1) * (i - 1) + (j - 1) * (j - 1) + (k - 1) * (k - 1);
          volatile float e = (float)exp(-2.0 * (double)d2);
          volatile float gg = factor * e;
          g[o++] = gg;
        }
    volatile float r[8];
    for (int j = 0; j < 8; ++j) r[j] = g[j];
    for (int j = 0; j < 8; ++j) r[j] = r[j] + g[8 + j];
    for (int j = 0; j < 8; ++j) r[j] = r[j] + g[16 + j];
    volatile float t01 = r[0] + r[1];
    volatile float t23 = r[2] + r[3];
    volatile float t45 = r[4] + r[5];
    volatile float t67 = r[6] + r[7];
    volatile float h0 = t01 + t23;
    volatile float h1 = t45 + t67;
    volatile float s = h0 + h1;
    s = s + g[24];
    s = s + g[25];
    s = s + g[26];
    for (int t = 0; t < 27; ++t) {
      volatile float w = g[t] / s;
      wt.w[t] = w;
    }
  }
  // 4 distinct weight values by d^2 symmetry: center o=13, face o=12,
  // edge o=9, corner o=0 (all f32-identical within each class).
  W4d wd = {(double)wt.w[13], (double)wt.w[12], (double)wt.w[9], (double)wt.w[0]};

  dim3 blk(256);
  dim3 g27(WW / 2, 4, 27);  // zslab = 24
  dim3 g3(WW / 2, 8, 3);    // zslab = 12
  int vb = (NVOX + 255) / 256;

  // cv blur passes (pass 1 computes cv on the fly from src/tgt)
  blur_march_kernel<true><<<g27, blk, 0, stream>>>(nullptr, src, tgt, cv1, 24, wd);
  blur_march_kernel<false><<<g27, blk, 0, stream>>>(cv1, nullptr, nullptr, cv2, 24, wd);
  blur_march_kernel<false><<<g27, blk, 0, stream>>>(cv2, nullptr, nullptr, cv1, 24, wd);
  // initial argmax flow (cv2 now dead -> fa/fb live there)
  flow_kernel<<<vb, blk, 0, stream>>>(cv1, nullptr, 0.f, 0, fa);
  blur_march_kernel<false><<<g3, blk, 0, stream>>>(fa, nullptr, nullptr, fb, 12, wd);
  blur_march_kernel<false><<<g3, blk, 0, stream>>>(fb, nullptr, nullptr, fa, 12, wd);
  blur_march_kernel<false><<<g3, blk, 0, stream>>>(fa, nullptr, nullptr, fb, 12, wd);
  // six coupling iterations
  const float coefs[6] = {0.003f, 0.01f, 0.03f, 0.1f, 0.3f, 1.0f};
  for (int it = 0; it < 6; ++it) {
    flow_kernel<<<vb, blk, 0, stream>>>(cv1, fb, coefs[it], 1, fa);
    blur_march_kernel<false><<<g3, blk, 0, stream>>>(fa, nullptr, nullptr, fb, 12, wd);
    blur_march_kernel<false><<<g3, blk, 0, stream>>>(fb, nullptr, nullptr, fa, 12, wd);
    float* dst = (it == 5) ? out : fb;
    blur_march_kernel<false><<<g3, blk, 0, stream>>>(fa, nullptr, nullptr, dst, 12, wd);
  }
}

// Round 5
// 573.592 us; speedup vs baseline: 3.4128x; 2.2470x over previous
//
#include <hip/hip_runtime.h>
#include <math.h>

// Problem constants (reference: H, W, D = 96, 80, 128; KS=1 -> 27 offsets)
#define HH 96
#define WW 80
#define DD 128
#define SLICE (WW * DD)       // 10240
#define NVOX (HH * WW * DD)   // 983040

struct W4d { double w0, w1, w2, w3; };
struct Raw { float4 t[3]; float4 s[3]; };

__device__ __forceinline__ float4 zf4() { return make_float4(0.f, 0.f, 0.f, 0.f); }

// Depthwise 3x3x3 Gaussian blur, zero padding, f64 accumulation (correctly-
// rounded f32 conv up to ~1e-16 f64 reassociation). Thread owns 4 consecutive
// x (32 lanes = full 128-wide row, 8 rows/block), marches a z-slab with a
// 2-slice raw prefetch pipeline. x-halo via wave shfl (q-boundary => zero-pad).
// Per slice keep P = w0*c+w1*f+w2*e and Q = w1*c+w2*f+w3*e (d^2 weight classes);
// out(z) = P(z) + Q(z-1) + Q(z+1).
// FUSED: computes the cost volume -|src(shift o)-tgt| on the fly (src zero-pad),
// channel o = blockIdx.z.
template <bool FUSED>
__global__ __launch_bounds__(256) void blur4_kernel(
    const float* __restrict__ in, const float* __restrict__ src,
    const float* __restrict__ tgt, float* __restrict__ out, int zslab, W4d w) {
  const int tid = threadIdx.x;
  const int lane = tid & 63;
  const int q = lane & 31;
  const int x0 = q << 2;
  const int y = blockIdx.x * 8 + ((tid >> 6) << 1) + (lane >> 5);
  const int c = blockIdx.z;
  const int z0 = blockIdx.y * zslab;
  const int z1 = min(z0 + zslab, HH);

  int oz = 0, oy = 0, ox = 0;
  if (FUSED) { oz = c / 9 - 1; oy = (c / 3) % 3 - 1; ox = c % 3 - 1; }
  const float* __restrict__ inc = FUSED ? (const float*)nullptr : (in + (size_t)c * NVOX);

  auto load_raw = [&](int zz, Raw& r) {
    #pragma unroll
    for (int dy = 0; dy < 3; ++dy) {
      int ry = y - 1 + dy;
      bool rv = ((unsigned)zz < (unsigned)HH) && ((unsigned)ry < (unsigned)WW);
      if (!FUSED) {
        r.t[dy] = rv ? *(const float4*)(inc + (size_t)zz * SLICE + ry * DD + x0) : zf4();
      } else {
        r.t[dy] = rv ? *(const float4*)(tgt + (size_t)zz * SLICE + ry * DD + x0) : zf4();
        int sz = zz + oz, sy = ry + oy;
        bool sv = rv && ((unsigned)sz < (unsigned)HH) && ((unsigned)sy < (unsigned)WW);
        r.s[dy] = sv ? *(const float4*)(src + (size_t)sz * SLICE + sy * DD + x0) : zf4();
      }
    }
  };

  // raw slice -> P[4], Q[4] (f64). All shfls are wave-uniform (no divergence).
  auto finish = [&](const Raw& r, double* P, double* Q) {
    float cc[3][4], cl[3], cr[3];
    #pragma unroll
    for (int dy = 0; dy < 3; ++dy) {
      float4 v;
      if (!FUSED) {
        v = r.t[dy];
      } else {
        float4 s4 = r.s[dy];
        float sl = __shfl_up(s4.w, 1);
        float sr = __shfl_down(s4.x, 1);
        if (q == 0) sl = 0.f;
        if (q == 31) sr = 0.f;
        float4 sh;
        if (ox < 0)      sh = make_float4(sl, s4.x, s4.y, s4.z);
        else if (ox > 0) sh = make_float4(s4.y, s4.z, s4.w, sr);
        else             sh = s4;
        float4 t4 = r.t[dy];
        v.x = -fabsf(__fsub_rn(sh.x, t4.x));
        v.y = -fabsf(__fsub_rn(sh.y, t4.y));
        v.z = -fabsf(__fsub_rn(sh.z, t4.z));
        v.w = -fabsf(__fsub_rn(sh.w, t4.w));
      }
      float l = __shfl_up(v.w, 1);
      float rr = __shfl_down(v.x, 1);
      cc[dy][0] = v.x; cc[dy][1] = v.y; cc[dy][2] = v.z; cc[dy][3] = v.w;
      cl[dy] = (q == 0) ? 0.f : l;
      cr[dy] = (q == 31) ? 0.f : rr;
    }
    auto hs = [&](int row, int i) -> double {
      float a = (i == 0) ? cl[row] : cc[row][i - 1];
      float b = (i == 3) ? cr[row] : cc[row][i + 1];
      return (double)a + (double)b;
    };
    #pragma unroll
    for (int i = 0; i < 4; ++i) {
      double c2 = (double)cc[1][i];
      double f2 = hs(1, i) + ((double)cc[0][i] + (double)cc[2][i]);
      double e2 = hs(0, i) + hs(2, i);
      P[i] = (w.w0 * c2 + w.w1 * f2) + w.w2 * e2;
      Q[i] = (w.w1 * c2 + w.w2 * f2) + w.w3 * e2;
    }
  };

  Raw rA, rB, rC, rD;
  double PA[4], QA[4], PB[4], QB[4], PC[4], QC[4];
  load_raw(z0 - 1, rA);
  load_raw(z0, rB);
  load_raw(z0 + 1, rC);
  finish(rA, PA, QA);
  finish(rB, PB, QB);
  float* ob = out + (size_t)c * NVOX + y * DD + x0;
  for (int z = z0; z < z1; ++z) {
    load_raw(z + 2, rD);          // prefetch 2 ahead (hides HBM latency)
    finish(rC, PC, QC);
    float4 o4;
    o4.x = (float)(PB[0] + (QA[0] + QC[0]));
    o4.y = (float)(PB[1] + (QA[1] + QC[1]));
    o4.z = (float)(PB[2] + (QA[2] + QC[2]));
    o4.w = (float)(PB[3] + (QA[3] + QC[3]));
    *(float4*)(ob + (size_t)z * SLICE) = o4;
    #pragma unroll
    for (int i = 0; i < 4; ++i) {
      PA[i] = PB[i]; QA[i] = QB[i];
      PB[i] = PC[i]; QB[i] = QC[i];
    }
    rC = rD;
  }
}

// coupled[o] = cv[o] - coeff * ||flow - offset_o||^2 (un-fused rounds, matching
// numpy). Reference argmax = exact-equality ties on y_o = f32(coupled_o/temp);
// the division's coarse grid merges 1-ulp near-ties, which then SUM offsets.
// Running scan: strict-improve resets sums, equality adds — identical result.
__global__ __launch_bounds__(256) void flow4_kernel(
    const float* __restrict__ cv, const float* __restrict__ fin,
    float coeff, int couple, float* __restrict__ fout) {
  const int t = blockIdx.x * blockDim.x + threadIdx.x;
  const size_t v = (size_t)t * 4;
  if (v >= (size_t)NVOX) return;
  float4 fz = zf4(), fy = zf4(), fx = zf4();
  if (couple) {
    fz = *(const float4*)(fin + v);
    fy = *(const float4*)(fin + (size_t)NVOX + v);
    fx = *(const float4*)(fin + 2 * (size_t)NVOX + v);
  }
  float best[4] = {-INFINITY, -INFINITY, -INFINITY, -INFINITY};
  float s0[4] = {0, 0, 0, 0}, s1[4] = {0, 0, 0, 0}, s2[4] = {0, 0, 0, 0};
  float fza[4] = {fz.x, fz.y, fz.z, fz.w};
  float fya[4] = {fy.x, fy.y, fy.z, fy.w};
  float fxa[4] = {fx.x, fx.y, fx.z, fx.w};
  #pragma unroll
  for (int o = 0; o < 27; ++o) {
    float4 c4 = *(const float4*)(cv + (size_t)o * NVOX + v);
    const float ozf = (float)(o / 9 - 1);
    const float oyf = (float)((o / 3) % 3 - 1);
    const float oxf = (float)(o % 3 - 1);
    float ca[4] = {c4.x, c4.y, c4.z, c4.w};
    #pragma unroll
    for (int i = 0; i < 4; ++i) {
      float cvv = ca[i];
      if (couple) {
        float dz = __fsub_rn(fza[i], ozf);
        float dy = __fsub_rn(fya[i], oyf);
        float dx = __fsub_rn(fxa[i], oxf);
        float d2 = __fadd_rn(__fadd_rn(__fmul_rn(dz, dz), __fmul_rn(dy, dy)),
                             __fmul_rn(dx, dx));
        cvv = __fsub_rn(cvv, __fmul_rn(coeff, d2));
      }
      float yv = __fdiv_rn(cvv, 5e-5f);   // tie-merging quantization step
      bool gt = yv > best[i];
      bool eq = yv == best[i];
      best[i] = gt ? yv : best[i];
      s0[i] = gt ? ozf : (eq ? s0[i] + ozf : s0[i]);
      s1[i] = gt ? oyf : (eq ? s1[i] + oyf : s1[i]);
      s2[i] = gt ? oxf : (eq ? s2[i] + oxf : s2[i]);
    }
  }
  *(float4*)(fout + v) = make_float4(s0[0], s0[1], s0[2], s0[3]);
  *(float4*)(fout + (size_t)NVOX + v) = make_float4(s1[0], s1[1], s1[2], s1[3]);
  *(float4*)(fout + 2 * (size_t)NVOX + v) = make_float4(s2[0], s2[1], s2[2], s2[3]);
}

extern "C" void kernel_launch(void* const* d_in, const int* in_sizes, int n_in,
                              void* d_out, int out_size, void* d_ws, size_t ws_size,
                              hipStream_t stream) {
  const float* src = (const float*)d_in[0];
  const float* tgt = (const float*)d_in[1];
  float* out = (float*)d_out;

  // Workspace layout (54*NVOX floats = ~212.3 MB):
  //   cv1: 27N  (final blurred cv, read-only for all 7 argmax stages)
  //   cv2: 27N  (ping buffer; dead after pass 3 -> flow buffers alias here)
  float* cv1 = (float*)d_ws;
  float* cv2 = cv1 + (size_t)27 * NVOX;
  float* fa = cv2;                       // aliased into dead cv2 region
  float* fb = cv2 + (size_t)3 * NVOX;

  // 3^3 Gaussian (sigma=0.5) weights, replicating the reference's f32 path
  // (factor*exp in f32, numpy pairwise f32 sum, f32 divide).
  float wt[27];
  {
    volatile float factor = (float)(1.0 / pow(2.0 * M_PI * 0.25, 1.5));
    float g[27];
    int o = 0;
    for (int i = 0; i < 3; ++i)
      for (int j = 0; j < 3; ++j)
        for (int k = 0; k < 3; ++k) {
          int d2 = (i - 1) * (i - 1) + (j - 1) * (j - 1) + (k - 1) * (k - 1);
          volatile float e = (float)exp(-2.0 * (double)d2);
          volatile float gg = factor * e;
          g[o++] = gg;
        }
    volatile float r[8];
    for (int j = 0; j < 8; ++j) r[j] = g[j];
    for (int j = 0; j < 8; ++j) r[j] = r[j] + g[8 + j];
    for (int j = 0; j < 8; ++j) r[j] = r[j] + g[16 + j];
    volatile float t01 = r[0] + r[1];
    volatile float t23 = r[2] + r[3];
    volatile float t45 = r[4] + r[5];
    volatile float t67 = r[6] + r[7];
    volatile float h0 = t01 + t23;
    volatile float h1 = t45 + t67;
    volatile float s = h0 + h1;
    s = s + g[24];
    s = s + g[25];
    s = s + g[26];
    for (int t = 0; t < 27; ++t) {
      volatile float w = g[t] / s;
      wt[t] = w;
    }
  }
  // 4 distinct weight values by d^2 symmetry: center o=13, face o=12,
  // edge o=9, corner o=0.
  W4d wd = {(double)wt[13], (double)wt[12], (double)wt[9], (double)wt[0]};

  dim3 blk(256);
  dim3 gBig(WW / 8, HH / 16, 27);  // zslab = 16
  dim3 gSm(WW / 8, HH / 8, 3);     // zslab = 8
  int fblocks = NVOX / 4 / 256;    // 960

  // cv blur passes (pass 1 computes cv on the fly from src/tgt)
  blur4_kernel<true><<<gBig, blk, 0, stream>>>(nullptr, src, tgt, cv1, 16, wd);
  blur4_kernel<false><<<gBig, blk, 0, stream>>>(cv1, nullptr, nullptr, cv2, 16, wd);
  blur4_kernel<false><<<gBig, blk, 0, stream>>>(cv2, nullptr, nullptr, cv1, 16, wd);
  // initial argmax flow (cv2 now dead -> fa/fb live there)
  flow4_kernel<<<fblocks, blk, 0, stream>>>(cv1, nullptr, 0.f, 0, fa);
  blur4_kernel<false><<<gSm, blk, 0, stream>>>(fa, nullptr, nullptr, fb, 8, wd);
  blur4_kernel<false><<<gSm, blk, 0, stream>>>(fb, nullptr, nullptr, fa, 8, wd);
  blur4_kernel<false><<<gSm, blk, 0, stream>>>(fa, nullptr, nullptr, fb, 8, wd);
  // six coupling iterations
  const float coefs[6] = {0.003f, 0.01f, 0.03f, 0.1f, 0.3f, 1.0f};
  for (int it = 0; it < 6; ++it) {
    flow4_kernel<<<fblocks, blk, 0, stream>>>(cv1, fb, coefs[it], 1, fa);
    blur4_kernel<false><<<gSm, blk, 0, stream>>>(fa, nullptr, nullptr, fb, 8, wd);
    blur4_kernel<false><<<gSm, blk, 0, stream>>>(fb, nullptr, nullptr, fa, 8, wd);
    float* dst = (it == 5) ? out : fb;
    blur4_kernel<false><<<gSm, blk, 0, stream>>>(fa, nullptr, nullptr, dst, 8, wd);
  }
}

// Round 6
// 557.765 us; speedup vs baseline: 3.5096x; 1.0284x over previous
//
#include <hip/hip_runtime.h>
#include <math.h>

// Problem constants (reference: H, W, D = 96, 80, 128; KS=1 -> 27 offsets)
#define HH 96
#define WW 80
#define DD 128
#define SLICE (WW * DD)       // 10240
#define NVOX (HH * WW * DD)   // 983040

struct W4d { double w0, w1, w2, w3; };
struct Raw { float4 t[3]; float4 s[3]; };

__device__ __forceinline__ float4 zf4() { return make_float4(0.f, 0.f, 0.f, 0.f); }

// Depthwise 3x3x3 Gaussian blur, zero padding, f64 accumulation (correctly-
// rounded f32 conv up to ~1e-16 f64 reassociation). Thread owns 4 consecutive
// x (32 lanes = full 128-wide row, 8 rows/block), marches a z-slab with a
// 2-slice raw prefetch pipeline. x-halo via wave shfl (q-boundary => zero-pad).
// Per slice keep P = w0*c+w1*f+w2*e and Q = w1*c+w2*f+w3*e (d^2 weight classes);
// out(z) = P(z) + Q(z-1) + Q(z+1).
// FUSED: computes the cost volume -|src(shift o)-tgt| on the fly (src zero-pad),
// channel o = blockIdx.z.
template <bool FUSED>
__global__ __launch_bounds__(256) void blur4_kernel(
    const float* __restrict__ in, const float* __restrict__ src,
    const float* __restrict__ tgt, float* __restrict__ out, int zslab, W4d w) {
  const int tid = threadIdx.x;
  const int lane = tid & 63;
  const int q = lane & 31;
  const int x0 = q << 2;
  const int y = blockIdx.x * 8 + ((tid >> 6) << 1) + (lane >> 5);
  const int c = blockIdx.z;
  const int z0 = blockIdx.y * zslab;
  const int z1 = min(z0 + zslab, HH);

  int oz = 0, oy = 0, ox = 0;
  if (FUSED) { oz = c / 9 - 1; oy = (c / 3) % 3 - 1; ox = c % 3 - 1; }
  const float* __restrict__ inc = FUSED ? (const float*)nullptr : (in + (size_t)c * NVOX);

  auto load_raw = [&](int zz, Raw& r) {
    #pragma unroll
    for (int dy = 0; dy < 3; ++dy) {
      int ry = y - 1 + dy;
      bool rv = ((unsigned)zz < (unsigned)HH) && ((unsigned)ry < (unsigned)WW);
      if (!FUSED) {
        r.t[dy] = rv ? *(const float4*)(inc + (size_t)zz * SLICE + ry * DD + x0) : zf4();
      } else {
        r.t[dy] = rv ? *(const float4*)(tgt + (size_t)zz * SLICE + ry * DD + x0) : zf4();
        int sz = zz + oz, sy = ry + oy;
        bool sv = rv && ((unsigned)sz < (unsigned)HH) && ((unsigned)sy < (unsigned)WW);
        r.s[dy] = sv ? *(const float4*)(src + (size_t)sz * SLICE + sy * DD + x0) : zf4();
      }
    }
  };

  // raw slice -> P[4], Q[4] (f64). All shfls are wave-uniform (no divergence).
  auto finish = [&](const Raw& r, double* P, double* Q) {
    float cc[3][4], cl[3], cr[3];
    #pragma unroll
    for (int dy = 0; dy < 3; ++dy) {
      float4 v;
      if (!FUSED) {
        v = r.t[dy];
      } else {
        float4 s4 = r.s[dy];
        float sl = __shfl_up(s4.w, 1);
        float sr = __shfl_down(s4.x, 1);
        if (q == 0) sl = 0.f;
        if (q == 31) sr = 0.f;
        float4 sh;
        if (ox < 0)      sh = make_float4(sl, s4.x, s4.y, s4.z);
        else if (ox > 0) sh = make_float4(s4.y, s4.z, s4.w, sr);
        else             sh = s4;
        float4 t4 = r.t[dy];
        v.x = -fabsf(__fsub_rn(sh.x, t4.x));
        v.y = -fabsf(__fsub_rn(sh.y, t4.y));
        v.z = -fabsf(__fsub_rn(sh.z, t4.z));
        v.w = -fabsf(__fsub_rn(sh.w, t4.w));
      }
      float l = __shfl_up(v.w, 1);
      float rr = __shfl_down(v.x, 1);
      cc[dy][0] = v.x; cc[dy][1] = v.y; cc[dy][2] = v.z; cc[dy][3] = v.w;
      cl[dy] = (q == 0) ? 0.f : l;
      cr[dy] = (q == 31) ? 0.f : rr;
    }
    auto hs = [&](int row, int i) -> double {
      float a = (i == 0) ? cl[row] : cc[row][i - 1];
      float b = (i == 3) ? cr[row] : cc[row][i + 1];
      return (double)a + (double)b;
    };
    #pragma unroll
    for (int i = 0; i < 4; ++i) {
      double c2 = (double)cc[1][i];
      double f2 = hs(1, i) + ((double)cc[0][i] + (double)cc[2][i]);
      double e2 = hs(0, i) + hs(2, i);
      P[i] = (w.w0 * c2 + w.w1 * f2) + w.w2 * e2;
      Q[i] = (w.w1 * c2 + w.w2 * f2) + w.w3 * e2;
    }
  };

  Raw rA, rB, rC, rD;
  double PA[4], QA[4], PB[4], QB[4], PC[4], QC[4];
  load_raw(z0 - 1, rA);
  load_raw(z0, rB);
  load_raw(z0 + 1, rC);
  finish(rA, PA, QA);
  finish(rB, PB, QB);
  float* ob = out + (size_t)c * NVOX + y * DD + x0;
  for (int z = z0; z < z1; ++z) {
    load_raw(z + 2, rD);          // prefetch 2 ahead (hides HBM latency)
    finish(rC, PC, QC);
    float4 o4;
    o4.x = (float)(PB[0] + (QA[0] + QC[0]));
    o4.y = (float)(PB[1] + (QA[1] + QC[1]));
    o4.z = (float)(PB[2] + (QA[2] + QC[2]));
    o4.w = (float)(PB[3] + (QA[3] + QC[3]));
    *(float4*)(ob + (size_t)z * SLICE) = o4;
    #pragma unroll
    for (int i = 0; i < 4; ++i) {
      PA[i] = PB[i]; QA[i] = QB[i];
      PB[i] = PC[i]; QB[i] = QC[i];
    }
    rC = rD;
  }
}

// coupled[o] = cv[o] - coeff * ||flow - offset_o||^2 (un-fused rounds, matching
// numpy). Reference argmax = exact-equality ties on y_o = f32(coupled_o/temp);
// the division's coarse grid merges 1-ulp near-ties, which then SUM offsets.
// Running scan: strict-improve resets sums, equality adds — identical result.
__global__ __launch_bounds__(256) void flow4_kernel(
    const float* __restrict__ cv, const float* __restrict__ fin,
    float coeff, int couple, float* __restrict__ fout) {
  const int t = blockIdx.x * blockDim.x + threadIdx.x;
  const size_t v = (size_t)t * 4;
  if (v >= (size_t)NVOX) return;
  float4 fz = zf4(), fy = zf4(), fx = zf4();
  if (couple) {
    fz = *(const float4*)(fin + v);
    fy = *(const float4*)(fin + (size_t)NVOX + v);
    fx = *(const float4*)(fin + 2 * (size_t)NVOX + v);
  }
  float best[4] = {-INFINITY, -INFINITY, -INFINITY, -INFINITY};
  float s0[4] = {0, 0, 0, 0}, s1[4] = {0, 0, 0, 0}, s2[4] = {0, 0, 0, 0};
  float fza[4] = {fz.x, fz.y, fz.z, fz.w};
  float fya[4] = {fy.x, fy.y, fy.z, fy.w};
  float fxa[4] = {fx.x, fx.y, fx.z, fx.w};
  #pragma unroll
  for (int o = 0; o < 27; ++o) {
    float4 c4 = *(const float4*)(cv + (size_t)o * NVOX + v);
    const float ozf = (float)(o / 9 - 1);
    const float oyf = (float)((o / 3) % 3 - 1);
    const float oxf = (float)(o % 3 - 1);
    float ca[4] = {c4.x, c4.y, c4.z, c4.w};
    #pragma unroll
    for (int i = 0; i < 4; ++i) {
      float cvv = ca[i];
      if (couple) {
        float dz = __fsub_rn(fza[i], ozf);
        float dy = __fsub_rn(fya[i], oyf);
        float dx = __fsub_rn(fxa[i], oxf);
        float d2 = __fadd_rn(__fadd_rn(__fmul_rn(dz, dz), __fmul_rn(dy, dy)),
                             __fmul_rn(dx, dx));
        cvv = __fsub_rn(cvv, __fmul_rn(coeff, d2));
      }
      float yv = __fdiv_rn(cvv, 5e-5f);   // tie-merging quantization step
      bool gt = yv > best[i];
      bool eq = yv == best[i];
      best[i] = gt ? yv : best[i];
      s0[i] = gt ? ozf : (eq ? s0[i] + ozf : s0[i]);
      s1[i] = gt ? oyf : (eq ? s1[i] + oyf : s1[i]);
      s2[i] = gt ? oxf : (eq ? s2[i] + oxf : s2[i]);
    }
  }
  *(float4*)(fout + v) = make_float4(s0[0], s0[1], s0[2], s0[3]);
  *(float4*)(fout + (size_t)NVOX + v) = make_float4(s1[0], s1[1], s1[2], s1[3]);
  *(float4*)(fout + 2 * (size_t)NVOX + v) = make_float4(s2[0], s2[1], s2[2], s2[3]);
}

extern "C" void kernel_launch(void* const* d_in, const int* in_sizes, int n_in,
                              void* d_out, int out_size, void* d_ws, size_t ws_size,
                              hipStream_t stream) {
  const float* src = (const float*)d_in[0];
  const float* tgt = (const float*)d_in[1];
  float* out = (float*)d_out;

  // Workspace layout (54*NVOX floats = ~212.3 MB):
  //   cv1: 27N  (final blurred cv, read-only for all 7 argmax stages)
  //   cv2: 27N  (ping buffer; dead after pass 3 -> flow buffers alias here)
  float* cv1 = (float*)d_ws;
  float* cv2 = cv1 + (size_t)27 * NVOX;
  float* fa = cv2;                       // aliased into dead cv2 region
  float* fb = cv2 + (size_t)3 * NVOX;

  // 3^3 Gaussian (sigma=0.5) weights, replicating the reference's f32 path
  // (factor*exp in f32, numpy pairwise f32 sum, f32 divide).
  float wt[27];
  {
    volatile float factor = (float)(1.0 / pow(2.0 * M_PI * 0.25, 1.5));
    float g[27];
    int o = 0;
    for (int i = 0; i < 3; ++i)
      for (int j = 0; j < 3; ++j)
        for (int k = 0; k < 3; ++k) {
          int d2 = (i - 1) * (i - 1) + (j - 1) * (j - 1) + (k - 1) * (k - 1);
          volatile float e = (float)exp(-2.0 * (double)d2);
          volatile float gg = factor * e;
          g[o++] = gg;
        }
    volatile float r[8];
    for (int j = 0; j < 8; ++j) r[j] = g[j];
    for (int j = 0; j < 8; ++j) r[j] = r[j] + g[8 + j];
    for (int j = 0; j < 8; ++j) r[j] = r[j] + g[16 + j];
    volatile float t01 = r[0] + r[1];
    volatile float t23 = r[2] + r[3];
    volatile float t45 = r[4] + r[5];
    volatile float t67 = r[6] + r[7];
    volatile float h0 = t01 + t23;
    volatile float h1 = t45 + t67;
    volatile float s = h0 + h1;
    s = s + g[24];
    s = s + g[25];
    s = s + g[26];
    for (int t = 0; t < 27; ++t) {
      volatile float w = g[t] / s;
      wt[t] = w;
    }
  }
  // 4 distinct weight values by d^2 symmetry: center o=13, face o=12,
  // edge o=9, corner o=0.
  W4d wd = {(double)wt[13], (double)wt[12], (double)wt[9], (double)wt[0]};

  dim3 blk(256);
  // Occupancy: VGPR=64, LDS=0 -> 8 blocks/CU possible. Need >=2048 blocks for
  // 256 CUs. zslab=8 -> 3240 blocks (big); zslab=3 -> 960 blocks (small).
  dim3 gBig(WW / 8, HH / 8, 27);   // zslab = 8
  dim3 gSm(WW / 8, HH / 3, 3);     // zslab = 3
  int fblocks = NVOX / 4 / 256;    // 960

  // cv blur passes (pass 1 computes cv on the fly from src/tgt)
  blur4_kernel<true><<<gBig, blk, 0, stream>>>(nullptr, src, tgt, cv1, 8, wd);
  blur4_kernel<false><<<gBig, blk, 0, stream>>>(cv1, nullptr, nullptr, cv2, 8, wd);
  blur4_kernel<false><<<gBig, blk, 0, stream>>>(cv2, nullptr, nullptr, cv1, 8, wd);
  // initial argmax flow (cv2 now dead -> fa/fb live there)
  flow4_kernel<<<fblocks, blk, 0, stream>>>(cv1, nullptr, 0.f, 0, fa);
  blur4_kernel<false><<<gSm, blk, 0, stream>>>(fa, nullptr, nullptr, fb, 3, wd);
  blur4_kernel<false><<<gSm, blk, 0, stream>>>(fb, nullptr, nullptr, fa, 3, wd);
  blur4_kernel<false><<<gSm, blk, 0, stream>>>(fa, nullptr, nullptr, fb, 3, wd);
  // six coupling iterations
  const float coefs[6] = {0.003f, 0.01f, 0.03f, 0.1f, 0.3f, 1.0f};
  for (int it = 0; it < 6; ++it) {
    flow4_kernel<<<fblocks, blk, 0, stream>>>(cv1, fb, coefs[it], 1, fa);
    blur4_kernel<false><<<gSm, blk, 0, stream>>>(fa, nullptr, nullptr, fb, 3, wd);
    blur4_kernel<false><<<gSm, blk, 0, stream>>>(fb, nullptr, nullptr, fa, 3, wd);
    float* dst = (it == 5) ? out : fb;
    blur4_kernel<false><<<gSm, blk, 0, stream>>>(fa, nullptr, nullptr, dst, 3, wd);
  }
}